// Round 9
// baseline (93519.659 us; speedup 1.0000x reference)
//
#include <hip/hip_runtime.h>

typedef __attribute__((ext_vector_type(8))) short short8v;
typedef __attribute__((ext_vector_type(4))) float f32x4;
typedef unsigned short u16;

#define MFMA_BF16(a,b,c) __builtin_amdgcn_mfma_f32_16x16x32_bf16((a),(b),(c),0,0,0)

static constexpr int Bb = 256, Tt = 512;
static constexpr int NBLK = 40, NTHR = 256;
// roles: bid 0-7 enc-chain (rows 32*bid), 8-15 zp-chain (+outdec ph2),
//        16-31 gru (ng=idx&7, mg=idx>>3; wave w -> rows mg*128+w*32), 32-39 phix

static constexpr size_t MU_OFF  = (size_t)Bb * Tt * 2;
static constexpr size_t LV_OFF  = MU_OFF  + (size_t)Bb * Tt * 256;
static constexpr size_t MUP_OFF = LV_OFF  + (size_t)Bb * Tt * 256;
static constexpr size_t LVP_OFF = MUP_OFF + (size_t)Bb * Tt * 256;

// ---------------- static device scratch ----------------
__device__ u16  g_wp_enc[196608];
__device__ u16  g_wp_pp[131072];
__device__ u16  g_wp_hh[786432];
__device__ u16  g_wp_mulv[131072];
__device__ u16  g_wp_mplp[131072];
__device__ u16  g_wp_phiz[65536];
__device__ u16  g_wp_ih[786432];
__device__ u16  g_wp_dec[12288];
__device__ u16  g_wp_phix[16384];
__device__ float g_h[2][131072];     // fp32 hidden, double-buffered (cross-barrier)
__device__ u16   g_hb[2][131072];    // bf16 hidden
__device__ u16   g_phx[2][65536];    // bf16 phi_x
__device__ u16   g_phizb[65536];     // bf16 phi_z (cross-barrier)
__device__ unsigned g_ctr;

__device__ __forceinline__ u16 f2bf(float f) {
  unsigned u = __builtin_bit_cast(unsigned, f);
  u += 0x7FFFu + ((u >> 16) & 1u);
  return (u16)(u >> 16);
}
__device__ __forceinline__ float bf2f(u16 v) {
  unsigned u = ((unsigned)v) << 16;
  return __builtin_bit_cast(float, u);
}

struct Args {
  const float *x, *eps;
  const float *b_phix, *b_enc, *b_mu, *b_lv, *b_pp, *b_mup, *b_lvp, *b_phiz, *b_dec, *b_ih, *b_hh;
  float *out;
};

// ---------------- weight pre-pack (unchanged layout) ----------------
__device__ __forceinline__ u16* sel_wp(int sel) {
  switch (sel) {
    case 0: return g_wp_enc;  case 1: return g_wp_pp;   case 2: return g_wp_hh;
    case 3: return g_wp_mulv; case 4: return g_wp_mplp; case 5: return g_wp_phiz;
    case 6: return g_wp_ih;   case 7: return g_wp_dec;  default: return g_wp_phix;
  }
}

__global__ void pack_w(const float* __restrict__ src, int KT, int Nsrc,
                       int sel, int nnStart, int nnCount, int colBase) {
  int gid = blockIdx.x * 256 + threadIdx.x;
  int total = nnCount * KT * 64;
  if (gid >= total) return;
  u16* dstBase = sel_wp(sel);
  int lane = gid & 63;
  int rem  = gid >> 6;
  int kk   = rem % KT;
  int nn   = nnStart + rem / KT;
  int col  = nn * 16 + (lane & 15) - colBase;
  int krow = kk * 32 + ((lane >> 4) << 3);
  bool ok = (col >= 0) && (col < Nsrc);
  u16* d = dstBase + ((size_t)(nn * KT + kk) * 64 + lane) * 8;
#pragma unroll
  for (int i = 0; i < 8; ++i)
    d[i] = ok ? f2bf(src[(size_t)(krow + i) * Nsrc + col]) : (u16)0;
}

// ---------------- fragment loads ----------------
__device__ __forceinline__ short8v loadB(const u16* wp, int KT, int nn, int kk, int lane) {
  return *(const short8v*)(wp + ((size_t)(nn * KT + kk) * 64 + lane) * 8);
}
__device__ __forceinline__ short8v loadA_bf(const u16* buf, int stride, int m0, int kcol, int lane) {
  return *(const short8v*)(buf + (size_t)(m0 + (lane & 15)) * stride + kcol + ((lane >> 4) << 3));
}
__device__ __forceinline__ short8v cvt8(const float* s) {
  short8v r;
#pragma unroll
  for (int i = 0; i < 8; ++i) r[i] = (short)f2bf(s[i]);
  return r;
}

__device__ __forceinline__ float sigm_(float x) { return 1.f / (1.f + __expf(-x)); }
__device__ __forceinline__ float tanh_(float x) {
  x = fminf(fmaxf(x, -15.f), 15.f);
  float e = __expf(2.f * x);
  return (e - 1.f) / (e + 1.f);
}

// ---------------- grid barrier (relaxed spin, one fence per side — R8-validated) ----------------
__device__ __forceinline__ void gbar(unsigned& epoch) {
  __syncthreads();
  if (threadIdx.x == 0) {
    __builtin_amdgcn_fence(__ATOMIC_RELEASE, "agent");
    __hip_atomic_fetch_add(&g_ctr, 1u, __ATOMIC_RELAXED, __HIP_MEMORY_SCOPE_AGENT);
    unsigned target = (++epoch) * (unsigned)NBLK;
    long guard = 0;
    while (__hip_atomic_load(&g_ctr, __ATOMIC_RELAXED, __HIP_MEMORY_SCOPE_AGENT) < target) {
      __builtin_amdgcn_s_sleep(8);
      if (++guard > (1l << 24)) break;
    }
    __builtin_amdgcn_fence(__ATOMIC_ACQUIRE, "agent");
  }
  __syncthreads();
}

// ---------------- chain jobs (block-local, LDS intermediates) ----------------
// LDS strides: bf16 tiles padded to 264 elems/row (528 B -> bank step 4, 2-way = free)

// enc = relu([phi_x | h] @ W_enc + b_enc): rows R..R+32, wave w does cols w*64..+64 -> LDS
__device__ void chain_enc(const Args& a, int R, int w, int t, u16* encb, int lane) {
  const u16* phx = g_phx[t & 1];
  const u16* hb  = g_hb[t & 1];
  const int n0 = w * 64, nn0 = n0 >> 4;
  f32x4 acc[2][4];
#pragma unroll
  for (int m = 0; m < 2; ++m)
#pragma unroll
    for (int f = 0; f < 4; ++f) acc[m][f] = (f32x4){0.f, 0.f, 0.f, 0.f};
  for (int kk = 0; kk < 24; ++kk) {
    short8v a0, a1;
    if (kk < 8) { a0 = loadA_bf(phx, 256, R, kk * 32, lane); a1 = loadA_bf(phx, 256, R + 16, kk * 32, lane); }
    else        { a0 = loadA_bf(hb, 512, R, (kk - 8) * 32, lane); a1 = loadA_bf(hb, 512, R + 16, (kk - 8) * 32, lane); }
#pragma unroll
    for (int f = 0; f < 4; ++f) {
      short8v b = loadB(g_wp_enc, 24, nn0 + f, kk, lane);
      acc[0][f] = MFMA_BF16(a0, b, acc[0][f]);
      acc[1][f] = MFMA_BF16(a1, b, acc[1][f]);
    }
  }
  const int cl = lane & 15, rb = (lane >> 4) << 2;
#pragma unroll
  for (int m = 0; m < 2; ++m)
#pragma unroll
    for (int f = 0; f < 4; ++f) {
      int col = n0 + f * 16 + cl;
      float bb = a.b_enc[col];
#pragma unroll
      for (int r = 0; r < 4; ++r) {
        int rl = m * 16 + rb + r;
        encb[rl * 264 + col] = f2bf(fmaxf(acc[m][f][r] + bb, 0.f));
      }
    }
}

// [mu|lv] tile j (cols j*64 of 512): A from LDS encb; out: bf16 LDS (for phiz) + NT fp32 d_out
__device__ void chain_mulv_one(const Args& a, int R, int j, int t, const u16* encb,
                               u16* muB, u16* lvB, int lane) {
  const int n0 = j * 64, nn0 = n0 >> 4;
  f32x4 acc[2][4];
#pragma unroll
  for (int m = 0; m < 2; ++m)
#pragma unroll
    for (int f = 0; f < 4; ++f) acc[m][f] = (f32x4){0.f, 0.f, 0.f, 0.f};
  for (int kk = 0; kk < 8; ++kk) {
    short8v a0 = loadA_bf(encb, 264, 0, kk * 32, lane);
    short8v a1 = loadA_bf(encb, 264, 16, kk * 32, lane);
#pragma unroll
    for (int f = 0; f < 4; ++f) {
      short8v b = loadB(g_wp_mulv, 8, nn0 + f, kk, lane);
      acc[0][f] = MFMA_BF16(a0, b, acc[0][f]);
      acc[1][f] = MFMA_BF16(a1, b, acc[1][f]);
    }
  }
  const int cl = lane & 15, rb = (lane >> 4) << 2;
#pragma unroll
  for (int m = 0; m < 2; ++m)
#pragma unroll
    for (int f = 0; f < 4; ++f) {
      int col = n0 + f * 16 + cl;
      bool isMu = col < 256;
      int c = isMu ? col : col - 256;
      float bb = isMu ? a.b_mu[c] : a.b_lv[c];
#pragma unroll
      for (int r = 0; r < 4; ++r) {
        int rl = m * 16 + rb + r;
        float v = acc[m][f][r] + bb;
        (isMu ? muB : lvB)[rl * 264 + c] = f2bf(v);
        __builtin_nontemporal_store(v,
          &a.out[(isMu ? MU_OFF : LV_OFF) + ((size_t)(R + rl) * 512 + t) * 256 + c]);
      }
    }
}

// phi_z = relu(z @ W_phiz + b), z built from LDS mu/lv + global eps; out -> global phizb
__device__ void chain_phiz(const Args& a, int R, int w, int t, const u16* muB, const u16* lvB, int lane) {
  const int n0 = w * 64, nn0 = n0 >> 4;
  f32x4 acc[2][4];
#pragma unroll
  for (int m = 0; m < 2; ++m)
#pragma unroll
    for (int f = 0; f < 4; ++f) acc[m][f] = (f32x4){0.f, 0.f, 0.f, 0.f};
  for (int kk = 0; kk < 8; ++kk) {
    short8v av[2];
#pragma unroll
    for (int m = 0; m < 2; ++m) {
      int rl = m * 16 + (lane & 15);
      int kc = kk * 32 + ((lane >> 4) << 3);
      const u16* mp = muB + rl * 264 + kc;
      const u16* lp = lvB + rl * 264 + kc;
      const float* ep = a.eps + ((size_t)(R + rl) * 512 + t) * 256 + kc;
#pragma unroll
      for (int i = 0; i < 8; ++i) {
        float e = __builtin_nontemporal_load(ep + i);
        av[m][i] = (short)f2bf(bf2f(mp[i]) + e * __expf(0.5f * bf2f(lp[i])));
      }
    }
#pragma unroll
    for (int f = 0; f < 4; ++f) {
      short8v b = loadB(g_wp_phiz, 8, nn0 + f, kk, lane);
      acc[0][f] = MFMA_BF16(av[0], b, acc[0][f]);
      acc[1][f] = MFMA_BF16(av[1], b, acc[1][f]);
    }
  }
  const int cl = lane & 15, rb = (lane >> 4) << 2;
#pragma unroll
  for (int m = 0; m < 2; ++m)
#pragma unroll
    for (int f = 0; f < 4; ++f) {
      int col = n0 + f * 16 + cl;
      float bb = a.b_phiz[col];
#pragma unroll
      for (int r = 0; r < 4; ++r) {
        int row = R + m * 16 + rb + r;
        g_phizb[(size_t)row * 256 + col] = f2bf(fmaxf(acc[m][f][r] + bb, 0.f));
      }
    }
}

// zp = relu(h @ W_pp + b_pp) -> LDS zpb
__device__ void chain_zp(const Args& a, int R, int w, int t, u16* zpb, int lane) {
  const u16* hb = g_hb[t & 1];
  const int n0 = w * 64, nn0 = n0 >> 4;
  f32x4 acc[2][4];
#pragma unroll
  for (int m = 0; m < 2; ++m)
#pragma unroll
    for (int f = 0; f < 4; ++f) acc[m][f] = (f32x4){0.f, 0.f, 0.f, 0.f};
  for (int kk = 0; kk < 16; ++kk) {
    short8v a0 = loadA_bf(hb, 512, R, kk * 32, lane);
    short8v a1 = loadA_bf(hb, 512, R + 16, kk * 32, lane);
#pragma unroll
    for (int f = 0; f < 4; ++f) {
      short8v b = loadB(g_wp_pp, 16, nn0 + f, kk, lane);
      acc[0][f] = MFMA_BF16(a0, b, acc[0][f]);
      acc[1][f] = MFMA_BF16(a1, b, acc[1][f]);
    }
  }
  const int cl = lane & 15, rb = (lane >> 4) << 2;
#pragma unroll
  for (int m = 0; m < 2; ++m)
#pragma unroll
    for (int f = 0; f < 4; ++f) {
      int col = n0 + f * 16 + cl;
      float bb = a.b_pp[col];
#pragma unroll
      for (int r = 0; r < 4; ++r) {
        int rl = m * 16 + rb + r;
        zpb[rl * 264 + col] = f2bf(fmaxf(acc[m][f][r] + bb, 0.f));
      }
    }
}

// [mup|lvp] tile j: A from LDS zpb; NT d_out only
__device__ void chain_mplp_one(const Args& a, int R, int j, int t, const u16* zpb, int lane) {
  const int n0 = j * 64, nn0 = n0 >> 4;
  f32x4 acc[2][4];
#pragma unroll
  for (int m = 0; m < 2; ++m)
#pragma unroll
    for (int f = 0; f < 4; ++f) acc[m][f] = (f32x4){0.f, 0.f, 0.f, 0.f};
  for (int kk = 0; kk < 8; ++kk) {
    short8v a0 = loadA_bf(zpb, 264, 0, kk * 32, lane);
    short8v a1 = loadA_bf(zpb, 264, 16, kk * 32, lane);
#pragma unroll
    for (int f = 0; f < 4; ++f) {
      short8v b = loadB(g_wp_mplp, 8, nn0 + f, kk, lane);
      acc[0][f] = MFMA_BF16(a0, b, acc[0][f]);
      acc[1][f] = MFMA_BF16(a1, b, acc[1][f]);
    }
  }
  const int cl = lane & 15, rb = (lane >> 4) << 2;
#pragma unroll
  for (int m = 0; m < 2; ++m)
#pragma unroll
    for (int f = 0; f < 4; ++f) {
      int col = n0 + f * 16 + cl;
      bool isMu = col < 256;
      int c = isMu ? col : col - 256;
      float bb = isMu ? a.b_mup[c] : a.b_lvp[c];
#pragma unroll
      for (int r = 0; r < 4; ++r) {
        int rl = m * 16 + rb + r;
        __builtin_nontemporal_store(acc[m][f][r] + bb,
          &a.out[(isMu ? MUP_OFF : LVP_OFF) + ((size_t)(R + rl) * 512 + t) * 256 + c]);
      }
    }
}

// phi_x(tt): global x -> global g_phx[tt&1]; j in [0,32)
__device__ void job_phix(const Args& a, int j, int tt, int lane) {
  u16* dst = g_phx[tt & 1];
  const int m0 = (j >> 2) * 32, n0 = (j & 3) * 64, nn0 = n0 >> 4;
  const float* xb = a.x + (size_t)tt * 64;
  f32x4 acc[2][4];
#pragma unroll
  for (int m = 0; m < 2; ++m)
#pragma unroll
    for (int f = 0; f < 4; ++f) acc[m][f] = (f32x4){0.f, 0.f, 0.f, 0.f};
  for (int kk = 0; kk < 2; ++kk) {
    int kc = kk * 32 + ((lane >> 4) << 3);
    short8v a0 = cvt8(xb + (size_t)(m0 + (lane & 15)) * 32768 + kc);
    short8v a1 = cvt8(xb + (size_t)(m0 + 16 + (lane & 15)) * 32768 + kc);
#pragma unroll
    for (int f = 0; f < 4; ++f) {
      short8v b = loadB(g_wp_phix, 2, nn0 + f, kk, lane);
      acc[0][f] = MFMA_BF16(a0, b, acc[0][f]);
      acc[1][f] = MFMA_BF16(a1, b, acc[1][f]);
    }
  }
  const int cl = lane & 15, rb = (lane >> 4) << 2;
#pragma unroll
  for (int m = 0; m < 2; ++m)
#pragma unroll
    for (int f = 0; f < 4; ++f) {
      int col = n0 + f * 16 + cl;
      float bb = a.b_phix[col];
#pragma unroll
      for (int r = 0; r < 4; ++r) {
        int row = m0 + m * 16 + rb + r;
        dst[(size_t)row * 256 + col] = f2bf(fmaxf(acc[m][f][r] + bb, 0.f));
      }
    }
}

// out = relu([phi_z | h] @ W_dec + b_dec); j in [0,8), phase 2
__device__ void job_outdec(const Args& a, int j, int t, int lane) {
  const u16* hb = g_hb[t & 1];
  const int m0 = j * 32;
  f32x4 acc[2];
  acc[0] = (f32x4){0.f, 0.f, 0.f, 0.f};
  acc[1] = (f32x4){0.f, 0.f, 0.f, 0.f};
  for (int kk = 0; kk < 24; ++kk) {
    short8v a0, a1;
    if (kk < 8) { a0 = loadA_bf(g_phizb, 256, m0, kk * 32, lane); a1 = loadA_bf(g_phizb, 256, m0 + 16, kk * 32, lane); }
    else        { a0 = loadA_bf(hb, 512, m0, (kk - 8) * 32, lane); a1 = loadA_bf(hb, 512, m0 + 16, (kk - 8) * 32, lane); }
    short8v b = loadB(g_wp_dec, 24, 0, kk, lane);
    acc[0] = MFMA_BF16(a0, b, acc[0]);
    acc[1] = MFMA_BF16(a1, b, acc[1]);
  }
  const int cl = lane & 15, rb = (lane >> 4) << 2;
  if (cl < 2) {
#pragma unroll
    for (int m = 0; m < 2; ++m)
#pragma unroll
      for (int r = 0; r < 4; ++r) {
        int row = m0 + m * 16 + rb + r;
        float v = fmaxf(acc[m][r] + a.b_dec[cl], 0.f);
        __builtin_nontemporal_store(v, &a.out[(size_t)row * 1024 + (size_t)t * 2 + cl]);
      }
  }
}

// ---------------- persistent kernel ----------------
__global__ __launch_bounds__(NTHR) void vrnn_main(Args a) {
  extern __shared__ char smem[];
  const int tid = threadIdx.x, lane = tid & 63, w = tid >> 6, bid = blockIdx.x;
  unsigned epoch = 0;

  u16* encb = (u16*)smem;                    // [32][264] bf16
  u16* muB  = (u16*)(smem + 16896);          // [32][264] bf16
  u16* lvB  = (u16*)(smem + 33792);          // [32][264] bf16
  u16* zpb  = (u16*)smem;                    // zp-chain blocks reuse base

  // gru role constants
  const bool isGru = (bid >= 16 && bid < 32);
  int gng = 0, gm0 = 0;
  if (isGru) { int idx = bid - 16; gng = idx & 7; gm0 = (idx >> 3) * 128 + w * 32; }

  // prologue: zero h/hb, phi_x(0)
  for (int g = bid * NTHR + tid; g < 131072; g += NBLK * NTHR) {
    g_h[0][g] = 0.f;
    g_hb[0][g] = 0;
  }
  if (bid >= 32) job_phix(a, (bid - 32) * 4 + w, 0, lane);
  gbar(epoch);

  for (int t = 0; t < Tt; ++t) {
    f32x4 arz[2][2][4];  // r,z accumulators (gh then +gi), gru only — live across barrier
    f32x4 ahn[2][4];     // hn (gh-only) accumulator

    // ---------------- phase 1 ----------------
    if (bid < 8) {
      int R = bid * 32;
      chain_enc(a, R, w, t, encb, lane);
      __syncthreads();
      chain_mulv_one(a, R, w, t, encb, muB, lvB, lane);
      chain_mulv_one(a, R, w + 4, t, encb, muB, lvB, lane);
      __syncthreads();
      chain_phiz(a, R, w, t, muB, lvB, lane);
    } else if (bid < 16) {
      int R = (bid - 8) * 32;
      chain_zp(a, R, w, t, zpb, lane);
      __syncthreads();
      chain_mplp_one(a, R, w, t, zpb, lane);
      chain_mplp_one(a, R, w + 4, t, zpb, lane);
    } else if (isGru) {
      // gh = h @ W_hh into registers (held across the barrier)
#pragma unroll
      for (int m = 0; m < 2; ++m) {
#pragma unroll
        for (int g = 0; g < 2; ++g)
#pragma unroll
          for (int f = 0; f < 4; ++f) arz[m][g][f] = (f32x4){0.f, 0.f, 0.f, 0.f};
#pragma unroll
        for (int f = 0; f < 4; ++f) ahn[m][f] = (f32x4){0.f, 0.f, 0.f, 0.f};
      }
      const u16* hb = g_hb[t & 1];
      for (int kk = 0; kk < 16; ++kk) {
        short8v a0 = loadA_bf(hb, 512, gm0, kk * 32, lane);
        short8v a1 = loadA_bf(hb, 512, gm0 + 16, kk * 32, lane);
#pragma unroll
        for (int g = 0; g < 2; ++g)
#pragma unroll
          for (int f = 0; f < 4; ++f) {
            short8v b = loadB(g_wp_hh, 16, g * 32 + gng * 4 + f, kk, lane);
            arz[0][g][f] = MFMA_BF16(a0, b, arz[0][g][f]);
            arz[1][g][f] = MFMA_BF16(a1, b, arz[1][g][f]);
          }
#pragma unroll
        for (int f = 0; f < 4; ++f) {
          short8v b = loadB(g_wp_hh, 16, 64 + gng * 4 + f, kk, lane);
          ahn[0][f] = MFMA_BF16(a0, b, ahn[0][f]);
          ahn[1][f] = MFMA_BF16(a1, b, ahn[1][f]);
        }
      }
    } else {
      if (t + 1 < Tt) job_phix(a, (bid - 32) * 4 + w, t + 1, lane);
    }
    gbar(epoch);

    // ---------------- phase 2 ----------------
    if (isGru) {
      f32x4 ain[2][4];
#pragma unroll
      for (int m = 0; m < 2; ++m)
#pragma unroll
        for (int f = 0; f < 4; ++f) ain[m][f] = (f32x4){0.f, 0.f, 0.f, 0.f};
      const u16* phx = g_phx[t & 1];
      for (int kk = 0; kk < 16; ++kk) {
        short8v a0, a1;
        if (kk < 8) { a0 = loadA_bf(phx, 256, gm0, kk * 32, lane); a1 = loadA_bf(phx, 256, gm0 + 16, kk * 32, lane); }
        else        { a0 = loadA_bf(g_phizb, 256, gm0, (kk - 8) * 32, lane); a1 = loadA_bf(g_phizb, 256, gm0 + 16, (kk - 8) * 32, lane); }
#pragma unroll
        for (int g = 0; g < 2; ++g)
#pragma unroll
          for (int f = 0; f < 4; ++f) {
            short8v b = loadB(g_wp_ih, 16, g * 32 + gng * 4 + f, kk, lane);
            arz[0][g][f] = MFMA_BF16(a0, b, arz[0][g][f]);
            arz[1][g][f] = MFMA_BF16(a1, b, arz[1][g][f]);
          }
#pragma unroll
        for (int f = 0; f < 4; ++f) {
          short8v b = loadB(g_wp_ih, 16, 64 + gng * 4 + f, kk, lane);
          ain[0][f] = MFMA_BF16(a0, b, ain[0][f]);
          ain[1][f] = MFMA_BF16(a1, b, ain[1][f]);
        }
      }
      // GRU epilogue
      const float* ho = g_h[t & 1];
      float* hn_ = g_h[(t + 1) & 1];
      u16* hbn = g_hb[(t + 1) & 1];
      const int cl = lane & 15, rb = (lane >> 4) << 2;
#pragma unroll
      for (int f = 0; f < 4; ++f) {
        int jcol = gng * 64 + f * 16 + cl;
        float br = a.b_ih[jcol] + a.b_hh[jcol];
        float bz = a.b_ih[512 + jcol] + a.b_hh[512 + jcol];
        float bin = a.b_ih[1024 + jcol];
        float bhn = a.b_hh[1024 + jcol];
#pragma unroll
        for (int m = 0; m < 2; ++m)
#pragma unroll
          for (int r = 0; r < 4; ++r) {
            int row = gm0 + m * 16 + rb + r;
            float rg = sigm_(arz[m][0][f][r] + br);
            float zg = sigm_(arz[m][1][f][r] + bz);
            float ngate = tanh_(ain[m][f][r] + bin + rg * (ahn[m][f][r] + bhn));
            float hold = ho[(size_t)row * 512 + jcol];
            float hv = (1.f - zg) * ngate + zg * hold;
            hn_[(size_t)row * 512 + jcol] = hv;
            hbn[(size_t)row * 512 + jcol] = f2bf(hv);
          }
      }
    } else if (bid >= 8 && bid < 16 && w == 0) {
      job_outdec(a, bid - 8, t, lane);
    }
    gbar(epoch);
  }
}

// ---------------- host launch ----------------
extern "C" void kernel_launch(void* const* d_in, const int* in_sizes, int n_in,
                              void* d_out, int out_size, void* d_ws, size_t ws_size,
                              hipStream_t stream) {
  const float* x      = (const float*)d_in[0];
  const float* eps    = (const float*)d_in[1];
  const float* W_phix = (const float*)d_in[2];  const float* b_phix = (const float*)d_in[3];
  const float* W_enc  = (const float*)d_in[4];  const float* b_enc  = (const float*)d_in[5];
  const float* W_mu   = (const float*)d_in[6];  const float* b_mu   = (const float*)d_in[7];
  const float* W_lv   = (const float*)d_in[8];  const float* b_lv   = (const float*)d_in[9];
  const float* W_pp   = (const float*)d_in[10]; const float* b_pp   = (const float*)d_in[11];
  const float* W_mup  = (const float*)d_in[12]; const float* b_mup  = (const float*)d_in[13];
  const float* W_lvp  = (const float*)d_in[14]; const float* b_lvp  = (const float*)d_in[15];
  const float* W_phiz = (const float*)d_in[16]; const float* b_phiz = (const float*)d_in[17];
  const float* W_dec  = (const float*)d_in[18]; const float* b_dec  = (const float*)d_in[19];
  const float* W_ih   = (const float*)d_in[20];
  const float* W_hh   = (const float*)d_in[21];
  const float* b_ih   = (const float*)d_in[22];
  const float* b_hh   = (const float*)d_in[23];
  (void)d_ws; (void)ws_size; (void)in_sizes; (void)n_in; (void)out_size;

  void* ctrAddr = nullptr;
  (void)hipGetSymbolAddress(&ctrAddr, HIP_SYMBOL(g_ctr));
  (void)hipMemsetAsync(ctrAddr, 0, sizeof(unsigned), stream);

  auto packL = [&](const float* src, int KT, int Nsrc, int sel, int nnStart, int nnCount, int colBase) {
    int total = nnCount * KT * 64;
    pack_w<<<(total + 255) / 256, 256, 0, stream>>>(src, KT, Nsrc, sel, nnStart, nnCount, colBase);
  };
  packL(W_enc, 24, 256, 0, 0, 16, 0);
  packL(W_pp, 16, 256, 1, 0, 16, 0);
  packL(W_hh, 16, 1536, 2, 0, 96, 0);
  packL(W_mu, 8, 256, 3, 0, 16, 0);
  packL(W_lv, 8, 256, 3, 16, 16, 256);
  packL(W_mup, 8, 256, 4, 0, 16, 0);
  packL(W_lvp, 8, 256, 4, 16, 16, 256);
  packL(W_phiz, 8, 256, 5, 0, 16, 0);
  packL(W_ih, 16, 1536, 6, 0, 96, 0);
  packL(W_dec, 24, 2, 7, 0, 1, 0);
  packL(W_phix, 2, 256, 8, 0, 16, 0);

  Args a;
  a.x = x; a.eps = eps;
  a.b_phix = b_phix; a.b_enc = b_enc; a.b_mu = b_mu; a.b_lv = b_lv; a.b_pp = b_pp;
  a.b_mup = b_mup; a.b_lvp = b_lvp; a.b_phiz = b_phiz; a.b_dec = b_dec; a.b_ih = b_ih; a.b_hh = b_hh;
  a.out = (float*)d_out;

  vrnn_main<<<NBLK, NTHR, 50688, stream>>>(a);
}

// Round 10
// 77424.298 us; speedup vs baseline: 1.2079x; 1.2079x over previous
//
#include <hip/hip_runtime.h>

typedef __attribute__((ext_vector_type(8))) short short8v;
typedef __attribute__((ext_vector_type(4))) float f32x4;
typedef unsigned short u16;
typedef unsigned long long u64;

#define MFMA_BF16(a,b,c) __builtin_amdgcn_mfma_f32_16x16x32_bf16((a),(b),(c),0,0,0)

static constexpr int Bb = 256, Tt = 512;
static constexpr int NBLK = 56, NTHR = 256;
// roles: 0-7 enc-chain (32 rows), 8-15 zp-chain (32 rows),
//        16-47 gru (wave gw=(bid-16)*4+w: rows (gw>>3)*16, cols (gw&7)*64),
//        48-55 phix (ph1, t+1) + outdec (ph2, w0)

static constexpr size_t MU_OFF  = (size_t)Bb * Tt * 2;
static constexpr size_t LV_OFF  = MU_OFF  + (size_t)Bb * Tt * 256;
static constexpr size_t MUP_OFF = LV_OFF  + (size_t)Bb * Tt * 256;
static constexpr size_t LVP_OFF = MUP_OFF + (size_t)Bb * Tt * 256;

// ---------------- static device scratch ----------------
__device__ u16  g_wp_enc[196608];
__device__ u16  g_wp_pp[131072];
__device__ u16  g_wp_hh[786432];
__device__ u16  g_wp_mulv[131072];
__device__ u16  g_wp_mplp[131072];
__device__ u16  g_wp_phiz[65536];
__device__ u16  g_wp_ih[786432];
__device__ u16  g_wp_dec[12288];
__device__ u16  g_wp_phix[16384];
__device__ u16  g_hb[2][131072];    // bf16 hidden (cross-phase, write-through)
__device__ u16  g_phx[2][65536];    // bf16 phi_x   (cross-phase, write-through)
__device__ u16  g_phizb[65536];     // bf16 phi_z   (cross-phase, write-through)
__device__ unsigned g_ctr;

__device__ __forceinline__ u16 f2bf(float f) {
  unsigned u = __builtin_bit_cast(unsigned, f);
  u += 0x7FFFu + ((u >> 16) & 1u);
  return (u16)(u >> 16);
}
__device__ __forceinline__ float bf2f(u16 v) {
  unsigned u = ((unsigned)v) << 16;
  return __builtin_bit_cast(float, u);
}

struct Args {
  const float *x, *eps;
  const float *b_phix, *b_enc, *b_mu, *b_lv, *b_pp, *b_mup, *b_lvp, *b_phiz, *b_dec, *b_ih, *b_hh;
  float *out;
};

// ---------------- coherent (write-through / L2-bypass) access helpers ----------------
// R8/R9 lesson [HW]: fences force every block to wbL2+inv (serialized walks + latency-bound
// refetch). Instead, cross-phase state uses agent-scope RELAXED atomics: sc-flagged
// loads/stores that hit the coherence point directly. No dirty L2 -> barrier needs NO fence.
__device__ __forceinline__ void st16(u16* p, u16 v) {
  __hip_atomic_store(p, v, __ATOMIC_RELAXED, __HIP_MEMORY_SCOPE_AGENT);
}
__device__ __forceinline__ short8v loadA_coh(const u16* buf, int stride, int m0, int kcol, int lane) {
  const u16* p = buf + (size_t)(m0 + (lane & 15)) * stride + kcol + ((lane >> 4) << 3);
  u64 lo = __hip_atomic_load((u64*)(void*)p,       __ATOMIC_RELAXED, __HIP_MEMORY_SCOPE_AGENT);
  u64 hi = __hip_atomic_load((u64*)(void*)(p + 4), __ATOMIC_RELAXED, __HIP_MEMORY_SCOPE_AGENT);
  union { u64 q[2]; short8v v; } u;
  u.q[0] = lo; u.q[1] = hi;
  return u.v;
}

// ---------------- weight pre-pack (unchanged layout) ----------------
__device__ __forceinline__ u16* sel_wp(int sel) {
  switch (sel) {
    case 0: return g_wp_enc;  case 1: return g_wp_pp;   case 2: return g_wp_hh;
    case 3: return g_wp_mulv; case 4: return g_wp_mplp; case 5: return g_wp_phiz;
    case 6: return g_wp_ih;   case 7: return g_wp_dec;  default: return g_wp_phix;
  }
}

__global__ void pack_w(const float* __restrict__ src, int KT, int Nsrc,
                       int sel, int nnStart, int nnCount, int colBase) {
  int gid = blockIdx.x * 256 + threadIdx.x;
  int total = nnCount * KT * 64;
  if (gid >= total) return;
  u16* dstBase = sel_wp(sel);
  int lane = gid & 63;
  int rem  = gid >> 6;
  int kk   = rem % KT;
  int nn   = nnStart + rem / KT;
  int col  = nn * 16 + (lane & 15) - colBase;
  int krow = kk * 32 + ((lane >> 4) << 3);
  bool ok = (col >= 0) && (col < Nsrc);
  u16* d = dstBase + ((size_t)(nn * KT + kk) * 64 + lane) * 8;
#pragma unroll
  for (int i = 0; i < 8; ++i)
    d[i] = ok ? f2bf(src[(size_t)(krow + i) * Nsrc + col]) : (u16)0;
}

// ---------------- fragment loads (cached weights / LDS) ----------------
__device__ __forceinline__ short8v loadB(const u16* wp, int KT, int nn, int kk, int lane) {
  return *(const short8v*)(wp + ((size_t)(nn * KT + kk) * 64 + lane) * 8);
}
__device__ __forceinline__ short8v loadA_bf(const u16* buf, int stride, int m0, int kcol, int lane) {
  return *(const short8v*)(buf + (size_t)(m0 + (lane & 15)) * stride + kcol + ((lane >> 4) << 3));
}
__device__ __forceinline__ short8v cvt8(const float* s) {
  short8v r;
#pragma unroll
  for (int i = 0; i < 8; ++i) r[i] = (short)f2bf(s[i]);
  return r;
}

__device__ __forceinline__ float sigm_(float x) { return 1.f / (1.f + __expf(-x)); }
__device__ __forceinline__ float tanh_(float x) {
  x = fminf(fmaxf(x, -15.f), 15.f);
  float e = __expf(2.f * x);
  return (e - 1.f) / (e + 1.f);
}

// ---------------- grid barrier: counter only, NO fences ----------------
// Stores are write-through (st16 / atomic); __syncthreads drains vmcnt before the
// signal, so data is at the coherence point before any block proceeds.
__device__ __forceinline__ void gbar(unsigned& epoch) {
  __syncthreads();
  if (threadIdx.x == 0) {
    __hip_atomic_fetch_add(&g_ctr, 1u, __ATOMIC_RELAXED, __HIP_MEMORY_SCOPE_AGENT);
    unsigned target = (++epoch) * (unsigned)NBLK;
    long guard = 0;
    while (__hip_atomic_load(&g_ctr, __ATOMIC_RELAXED, __HIP_MEMORY_SCOPE_AGENT) < target) {
      __builtin_amdgcn_s_sleep(2);
      if (++guard > (1l << 24)) break;  // never hard-hang
    }
  }
  __syncthreads();
}

// ---------------- chain jobs (block-local LDS intermediates, 32 rows) ----------------

// enc = relu([phi_x | h] @ W_enc + b_enc): wave w -> cols w*64
__device__ void chain_enc(const Args& a, int R, int w, int t, u16* encb, int lane) {
  const u16* phx = g_phx[t & 1];
  const u16* hb  = g_hb[t & 1];
  const int n0 = w * 64, nn0 = n0 >> 4;
  f32x4 acc[2][4];
#pragma unroll
  for (int m = 0; m < 2; ++m)
#pragma unroll
    for (int f = 0; f < 4; ++f) acc[m][f] = (f32x4){0.f, 0.f, 0.f, 0.f};
  for (int kk = 0; kk < 24; ++kk) {
    short8v a0, a1;
    if (kk < 8) { a0 = loadA_coh(phx, 256, R, kk * 32, lane); a1 = loadA_coh(phx, 256, R + 16, kk * 32, lane); }
    else        { a0 = loadA_coh(hb, 512, R, (kk - 8) * 32, lane); a1 = loadA_coh(hb, 512, R + 16, (kk - 8) * 32, lane); }
#pragma unroll
    for (int f = 0; f < 4; ++f) {
      short8v b = loadB(g_wp_enc, 24, nn0 + f, kk, lane);
      acc[0][f] = MFMA_BF16(a0, b, acc[0][f]);
      acc[1][f] = MFMA_BF16(a1, b, acc[1][f]);
    }
  }
  const int cl = lane & 15, rb = (lane >> 4) << 2;
#pragma unroll
  for (int m = 0; m < 2; ++m)
#pragma unroll
    for (int f = 0; f < 4; ++f) {
      int col = n0 + f * 16 + cl;
      float bb = a.b_enc[col];
#pragma unroll
      for (int r = 0; r < 4; ++r) {
        int rl = m * 16 + rb + r;
        encb[rl * 264 + col] = f2bf(fmaxf(acc[m][f][r] + bb, 0.f));
      }
    }
}

// [mu|lv] tile j: A from LDS encb; bf16 LDS out + NT fp32 d_out
__device__ void chain_mulv_one(const Args& a, int R, int j, int t, const u16* encb,
                               u16* muB, u16* lvB, int lane) {
  const int n0 = j * 64, nn0 = n0 >> 4;
  f32x4 acc[2][4];
#pragma unroll
  for (int m = 0; m < 2; ++m)
#pragma unroll
    for (int f = 0; f < 4; ++f) acc[m][f] = (f32x4){0.f, 0.f, 0.f, 0.f};
  for (int kk = 0; kk < 8; ++kk) {
    short8v a0 = loadA_bf(encb, 264, 0, kk * 32, lane);
    short8v a1 = loadA_bf(encb, 264, 16, kk * 32, lane);
#pragma unroll
    for (int f = 0; f < 4; ++f) {
      short8v b = loadB(g_wp_mulv, 8, nn0 + f, kk, lane);
      acc[0][f] = MFMA_BF16(a0, b, acc[0][f]);
      acc[1][f] = MFMA_BF16(a1, b, acc[1][f]);
    }
  }
  const int cl = lane & 15, rb = (lane >> 4) << 2;
#pragma unroll
  for (int m = 0; m < 2; ++m)
#pragma unroll
    for (int f = 0; f < 4; ++f) {
      int col = n0 + f * 16 + cl;
      bool isMu = col < 256;
      int c = isMu ? col : col - 256;
      float bb = isMu ? a.b_mu[c] : a.b_lv[c];
#pragma unroll
      for (int r = 0; r < 4; ++r) {
        int rl = m * 16 + rb + r;
        float v = acc[m][f][r] + bb;
        (isMu ? muB : lvB)[rl * 264 + c] = f2bf(v);
        __builtin_nontemporal_store(v,
          &a.out[(isMu ? MU_OFF : LV_OFF) + ((size_t)(R + rl) * 512 + t) * 256 + c]);
      }
    }
}

// phi_z: z from LDS mu/lv + eps; result -> g_phizb (write-through)
__device__ void chain_phiz(const Args& a, int R, int w, int t, const u16* muB, const u16* lvB, int lane) {
  const int n0 = w * 64, nn0 = n0 >> 4;
  f32x4 acc[2][4];
#pragma unroll
  for (int m = 0; m < 2; ++m)
#pragma unroll
    for (int f = 0; f < 4; ++f) acc[m][f] = (f32x4){0.f, 0.f, 0.f, 0.f};
  for (int kk = 0; kk < 8; ++kk) {
    short8v av[2];
#pragma unroll
    for (int m = 0; m < 2; ++m) {
      int rl = m * 16 + (lane & 15);
      int kc = kk * 32 + ((lane >> 4) << 3);
      const u16* mp = muB + rl * 264 + kc;
      const u16* lp = lvB + rl * 264 + kc;
      const float* ep = a.eps + ((size_t)(R + rl) * 512 + t) * 256 + kc;
#pragma unroll
      for (int i = 0; i < 8; ++i) {
        float e = __builtin_nontemporal_load(ep + i);
        av[m][i] = (short)f2bf(bf2f(mp[i]) + e * __expf(0.5f * bf2f(lp[i])));
      }
    }
#pragma unroll
    for (int f = 0; f < 4; ++f) {
      short8v b = loadB(g_wp_phiz, 8, nn0 + f, kk, lane);
      acc[0][f] = MFMA_BF16(av[0], b, acc[0][f]);
      acc[1][f] = MFMA_BF16(av[1], b, acc[1][f]);
    }
  }
  const int cl = lane & 15, rb = (lane >> 4) << 2;
#pragma unroll
  for (int m = 0; m < 2; ++m)
#pragma unroll
    for (int f = 0; f < 4; ++f) {
      int col = n0 + f * 16 + cl;
      float bb = a.b_phiz[col];
#pragma unroll
      for (int r = 0; r < 4; ++r) {
        int row = R + m * 16 + rb + r;
        st16(&g_phizb[(size_t)row * 256 + col], f2bf(fmaxf(acc[m][f][r] + bb, 0.f)));
      }
    }
}

// zp = relu(h @ W_pp + b_pp) -> LDS
__device__ void chain_zp(const Args& a, int R, int w, int t, u16* zpb, int lane) {
  const u16* hb = g_hb[t & 1];
  const int n0 = w * 64, nn0 = n0 >> 4;
  f32x4 acc[2][4];
#pragma unroll
  for (int m = 0; m < 2; ++m)
#pragma unroll
    for (int f = 0; f < 4; ++f) acc[m][f] = (f32x4){0.f, 0.f, 0.f, 0.f};
  for (int kk = 0; kk < 16; ++kk) {
    short8v a0 = loadA_coh(hb, 512, R, kk * 32, lane);
    short8v a1 = loadA_coh(hb, 512, R + 16, kk * 32, lane);
#pragma unroll
    for (int f = 0; f < 4; ++f) {
      short8v b = loadB(g_wp_pp, 16, nn0 + f, kk, lane);
      acc[0][f] = MFMA_BF16(a0, b, acc[0][f]);
      acc[1][f] = MFMA_BF16(a1, b, acc[1][f]);
    }
  }
  const int cl = lane & 15, rb = (lane >> 4) << 2;
#pragma unroll
  for (int m = 0; m < 2; ++m)
#pragma unroll
    for (int f = 0; f < 4; ++f) {
      int col = n0 + f * 16 + cl;
      float bb = a.b_pp[col];
#pragma unroll
      for (int r = 0; r < 4; ++r) {
        int rl = m * 16 + rb + r;
        zpb[rl * 264 + col] = f2bf(fmaxf(acc[m][f][r] + bb, 0.f));
      }
    }
}

// [mup|lvp] tile j: A from LDS zpb; NT d_out
__device__ void chain_mplp_one(const Args& a, int R, int j, int t, const u16* zpb, int lane) {
  const int n0 = j * 64, nn0 = n0 >> 4;
  f32x4 acc[2][4];
#pragma unroll
  for (int m = 0; m < 2; ++m)
#pragma unroll
    for (int f = 0; f < 4; ++f) acc[m][f] = (f32x4){0.f, 0.f, 0.f, 0.f};
  for (int kk = 0; kk < 8; ++kk) {
    short8v a0 = loadA_bf(zpb, 264, 0, kk * 32, lane);
    short8v a1 = loadA_bf(zpb, 264, 16, kk * 32, lane);
#pragma unroll
    for (int f = 0; f < 4; ++f) {
      short8v b = loadB(g_wp_mplp, 8, nn0 + f, kk, lane);
      acc[0][f] = MFMA_BF16(a0, b, acc[0][f]);
      acc[1][f] = MFMA_BF16(a1, b, acc[1][f]);
    }
  }
  const int cl = lane & 15, rb = (lane >> 4) << 2;
#pragma unroll
  for (int m = 0; m < 2; ++m)
#pragma unroll
    for (int f = 0; f < 4; ++f) {
      int col = n0 + f * 16 + cl;
      bool isMu = col < 256;
      int c = isMu ? col : col - 256;
      float bb = isMu ? a.b_mup[c] : a.b_lvp[c];
#pragma unroll
      for (int r = 0; r < 4; ++r) {
        int rl = m * 16 + rb + r;
        __builtin_nontemporal_store(acc[m][f][r] + bb,
          &a.out[(isMu ? MUP_OFF : LVP_OFF) + ((size_t)(R + rl) * 512 + t) * 256 + c]);
      }
    }
}

// phi_x(tt): x (cached) -> g_phx[tt&1] (write-through); j in [0,32)
__device__ void job_phix(const Args& a, int j, int tt, int lane) {
  u16* dst = g_phx[tt & 1];
  const int m0 = (j >> 2) * 32, n0 = (j & 3) * 64, nn0 = n0 >> 4;
  const float* xb = a.x + (size_t)tt * 64;
  f32x4 acc[2][4];
#pragma unroll
  for (int m = 0; m < 2; ++m)
#pragma unroll
    for (int f = 0; f < 4; ++f) acc[m][f] = (f32x4){0.f, 0.f, 0.f, 0.f};
  for (int kk = 0; kk < 2; ++kk) {
    int kc = kk * 32 + ((lane >> 4) << 3);
    short8v a0 = cvt8(xb + (size_t)(m0 + (lane & 15)) * 32768 + kc);
    short8v a1 = cvt8(xb + (size_t)(m0 + 16 + (lane & 15)) * 32768 + kc);
#pragma unroll
    for (int f = 0; f < 4; ++f) {
      short8v b = loadB(g_wp_phix, 2, nn0 + f, kk, lane);
      acc[0][f] = MFMA_BF16(a0, b, acc[0][f]);
      acc[1][f] = MFMA_BF16(a1, b, acc[1][f]);
    }
  }
  const int cl = lane & 15, rb = (lane >> 4) << 2;
#pragma unroll
  for (int m = 0; m < 2; ++m)
#pragma unroll
    for (int f = 0; f < 4; ++f) {
      int col = n0 + f * 16 + cl;
      float bb = a.b_phix[col];
#pragma unroll
      for (int r = 0; r < 4; ++r) {
        int row = m0 + m * 16 + rb + r;
        st16(&dst[(size_t)row * 256 + col], f2bf(fmaxf(acc[m][f][r] + bb, 0.f)));
      }
    }
}

// out = relu([phi_z | h] @ W_dec + b_dec); j in [0,8), ph2
__device__ void job_outdec(const Args& a, int j, int t, int lane) {
  const u16* hb = g_hb[t & 1];
  const int m0 = j * 32;
  f32x4 acc[2];
  acc[0] = (f32x4){0.f, 0.f, 0.f, 0.f};
  acc[1] = (f32x4){0.f, 0.f, 0.f, 0.f};
  for (int kk = 0; kk < 24; ++kk) {
    short8v a0, a1;
    if (kk < 8) { a0 = loadA_coh(g_phizb, 256, m0, kk * 32, lane); a1 = loadA_coh(g_phizb, 256, m0 + 16, kk * 32, lane); }
    else        { a0 = loadA_coh(hb, 512, m0, (kk - 8) * 32, lane); a1 = loadA_coh(hb, 512, m0 + 16, (kk - 8) * 32, lane); }
    short8v b = loadB(g_wp_dec, 24, 0, kk, lane);
    acc[0] = MFMA_BF16(a0, b, acc[0]);
    acc[1] = MFMA_BF16(a1, b, acc[1]);
  }
  const int cl = lane & 15, rb = (lane >> 4) << 2;
  if (cl < 2) {
#pragma unroll
    for (int m = 0; m < 2; ++m)
#pragma unroll
      for (int r = 0; r < 4; ++r) {
        int row = m0 + m * 16 + rb + r;
        float v = fmaxf(acc[m][r] + a.b_dec[cl], 0.f);
        __builtin_nontemporal_store(v, &a.out[(size_t)row * 1024 + (size_t)t * 2 + cl]);
      }
  }
}

// ---------------- persistent kernel ----------------
__global__ __launch_bounds__(NTHR) void vrnn_main(Args a) {
  extern __shared__ char smem[];
  const int tid = threadIdx.x, lane = tid & 63, w = tid >> 6, bid = blockIdx.x;
  unsigned epoch = 0;

  u16* encb = (u16*)smem;            // [32][264]
  u16* muB  = (u16*)(smem + 16896);
  u16* lvB  = (u16*)(smem + 33792);
  u16* zpb  = (u16*)smem;

  const bool isGru = (bid >= 16 && bid < 48);
  int gng = 0, gm0 = 0;
  if (isGru) { int gw = (bid - 16) * 4 + w; gng = gw & 7; gm0 = (gw >> 3) * 16; }

  // h slice lives in registers for the whole sequence (fp32): hreg[f][r] = h[gm0+rb+r][gng*64+f*16+cl]
  f32x4 hreg[4];
#pragma unroll
  for (int f = 0; f < 4; ++f) hreg[f] = (f32x4){0.f, 0.f, 0.f, 0.f};
  // gh accumulators held across the ph1->ph2 barrier
  f32x4 arz[2][4], ahn[4];

  // prologue: zero hb[0] (write-through), phi_x(0)
  for (int g = bid * NTHR + tid; g < 65536; g += NBLK * NTHR)
    __hip_atomic_store((unsigned*)g_hb[0] + g, 0u, __ATOMIC_RELAXED, __HIP_MEMORY_SCOPE_AGENT);
  if (bid >= 48) job_phix(a, (bid - 48) * 4 + w, 0, lane);
  gbar(epoch);

  for (int t = 0; t < Tt; ++t) {
    // ---------------- phase 1 ----------------
    if (bid < 8) {
      int R = bid * 32;
      chain_enc(a, R, w, t, encb, lane);
      __syncthreads();
      chain_mulv_one(a, R, w, t, encb, muB, lvB, lane);
      chain_mulv_one(a, R, w + 4, t, encb, muB, lvB, lane);
      __syncthreads();
      chain_phiz(a, R, w, t, muB, lvB, lane);
    } else if (bid < 16) {
      int R = (bid - 8) * 32;
      chain_zp(a, R, w, t, zpb, lane);
      __syncthreads();
      chain_mplp_one(a, R, w, t, zpb, lane);
      chain_mplp_one(a, R, w + 4, t, zpb, lane);
    } else if (isGru) {
      // gh = h @ W_hh slice into registers
#pragma unroll
      for (int g = 0; g < 2; ++g)
#pragma unroll
        for (int f = 0; f < 4; ++f) arz[g][f] = (f32x4){0.f, 0.f, 0.f, 0.f};
#pragma unroll
      for (int f = 0; f < 4; ++f) ahn[f] = (f32x4){0.f, 0.f, 0.f, 0.f};
      const u16* hb = g_hb[t & 1];
      for (int kk = 0; kk < 16; ++kk) {
        short8v a0 = loadA_coh(hb, 512, gm0, kk * 32, lane);
#pragma unroll
        for (int g = 0; g < 2; ++g)
#pragma unroll
          for (int f = 0; f < 4; ++f) {
            short8v b = loadB(g_wp_hh, 16, g * 32 + gng * 4 + f, kk, lane);
            arz[g][f] = MFMA_BF16(a0, b, arz[g][f]);
          }
#pragma unroll
        for (int f = 0; f < 4; ++f) {
          short8v b = loadB(g_wp_hh, 16, 64 + gng * 4 + f, kk, lane);
          ahn[f] = MFMA_BF16(a0, b, ahn[f]);
        }
      }
    } else {
      if (t + 1 < Tt) job_phix(a, (bid - 48) * 4 + w, t + 1, lane);
    }
    gbar(epoch);

    // ---------------- phase 2 ----------------
    if (isGru) {
      f32x4 ain[4];
#pragma unroll
      for (int f = 0; f < 4; ++f) ain[f] = (f32x4){0.f, 0.f, 0.f, 0.f};
      const u16* phx = g_phx[t & 1];
      for (int kk = 0; kk < 16; ++kk) {
        short8v a0 = (kk < 8) ? loadA_coh(phx, 256, gm0, kk * 32, lane)
                              : loadA_coh(g_phizb, 256, gm0, (kk - 8) * 32, lane);
#pragma unroll
        for (int g = 0; g < 2; ++g)
#pragma unroll
          for (int f = 0; f < 4; ++f) {
            short8v b = loadB(g_wp_ih, 16, g * 32 + gng * 4 + f, kk, lane);
            arz[g][f] = MFMA_BF16(a0, b, arz[g][f]);
          }
#pragma unroll
        for (int f = 0; f < 4; ++f) {
          short8v b = loadB(g_wp_ih, 16, 64 + gng * 4 + f, kk, lane);
          ain[f] = MFMA_BF16(a0, b, ain[f]);
        }
      }
      // GRU epilogue; h stays in registers, hb written through
      u16* hbn = g_hb[(t + 1) & 1];
      const int cl = lane & 15, rb = (lane >> 4) << 2;
#pragma unroll
      for (int f = 0; f < 4; ++f) {
        int jcol = gng * 64 + f * 16 + cl;
        float br = a.b_ih[jcol] + a.b_hh[jcol];
        float bz = a.b_ih[512 + jcol] + a.b_hh[512 + jcol];
        float bin = a.b_ih[1024 + jcol];
        float bhn = a.b_hh[1024 + jcol];
#pragma unroll
        for (int r = 0; r < 4; ++r) {
          int row = gm0 + rb + r;
          float rg = sigm_(arz[0][f][r] + br);
          float zg = sigm_(arz[1][f][r] + bz);
          float ngate = tanh_(ain[f][r] + bin + rg * (ahn[f][r] + bhn));
          float hv = (1.f - zg) * ngate + zg * hreg[f][r];
          hreg[f][r] = hv;
          st16(&hbn[(size_t)row * 512 + jcol], f2bf(hv));
        }
      }
    } else if (bid >= 48 && w == 0) {
      job_outdec(a, bid - 48, t, lane);
    }
    gbar(epoch);
  }
}

// ---------------- host launch ----------------
extern "C" void kernel_launch(void* const* d_in, const int* in_sizes, int n_in,
                              void* d_out, int out_size, void* d_ws, size_t ws_size,
                              hipStream_t stream) {
  const float* x      = (const float*)d_in[0];
  const float* eps    = (const float*)d_in[1];
  const float* W_phix = (const float*)d_in[2];  const float* b_phix = (const float*)d_in[3];
  const float* W_enc  = (const float*)d_in[4];  const float* b_enc  = (const float*)d_in[5];
  const float* W_mu   = (const float*)d_in[6];  const float* b_mu   = (const float*)d_in[7];
  const float* W_lv   = (const float*)d_in[8];  const float* b_lv   = (const float*)d_in[9];
  const float* W_pp   = (const float*)d_in[10]; const float* b_pp   = (const float*)d_in[11];
  const float* W_mup  = (const float*)d_in[12]; const float* b_mup  = (const float*)d_in[13];
  const float* W_lvp  = (const float*)d_in[14]; const float* b_lvp  = (const float*)d_in[15];
  const float* W_phiz = (const float*)d_in[16]; const float* b_phiz = (const float*)d_in[17];
  const float* W_dec  = (const float*)d_in[18]; const float* b_dec  = (const float*)d_in[19];
  const float* W_ih   = (const float*)d_in[20];
  const float* W_hh   = (const float*)d_in[21];
  const float* b_ih   = (const float*)d_in[22];
  const float* b_hh   = (const float*)d_in[23];
  (void)d_ws; (void)ws_size; (void)in_sizes; (void)n_in; (void)out_size;

  void* ctrAddr = nullptr;
  (void)hipGetSymbolAddress(&ctrAddr, HIP_SYMBOL(g_ctr));
  (void)hipMemsetAsync(ctrAddr, 0, sizeof(unsigned), stream);

  auto packL = [&](const float* src, int KT, int Nsrc, int sel, int nnStart, int nnCount, int colBase) {
    int total = nnCount * KT * 64;
    pack_w<<<(total + 255) / 256, 256, 0, stream>>>(src, KT, Nsrc, sel, nnStart, nnCount, colBase);
  };
  packL(W_enc, 24, 256, 0, 0, 16, 0);
  packL(W_pp, 16, 256, 1, 0, 16, 0);
  packL(W_hh, 16, 1536, 2, 0, 96, 0);
  packL(W_mu, 8, 256, 3, 0, 16, 0);
  packL(W_lv, 8, 256, 3, 16, 16, 256);
  packL(W_mup, 8, 256, 4, 0, 16, 0);
  packL(W_lvp, 8, 256, 4, 16, 16, 256);
  packL(W_phiz, 8, 256, 5, 0, 16, 0);
  packL(W_ih, 16, 1536, 6, 0, 96, 0);
  packL(W_dec, 24, 2, 7, 0, 1, 0);
  packL(W_phix, 2, 256, 8, 0, 16, 0);

  Args a;
  a.x = x; a.eps = eps;
  a.b_phix = b_phix; a.b_enc = b_enc; a.b_mu = b_mu; a.b_lv = b_lv; a.b_pp = b_pp;
  a.b_mup = b_mup; a.b_lvp = b_lvp; a.b_phiz = b_phiz; a.b_dec = b_dec; a.b_ih = b_ih; a.b_hh = b_hh;
  a.out = (float*)d_out;

  vrnn_main<<<NBLK, NTHR, 50688, stream>>>(a);
}